// Round 1
// baseline (2171.902 us; speedup 1.0000x reference)
//
#include <hip/hip_runtime.h>

// PopulationSNN: 3-layer LIF SNN, T=100 sequential steps, B=2048.
// R3: (a) GEMM1 computes TWO timesteps per W1 pass (halves W1 L2 traffic,
//     the ~0.7ms L2-stream term); x tiles get a dedicated 32KB LDS buffer.
//     (b) Layer-1 spikes are ~0.13% dense (var analysis) -> GEMM2 skips
//     all-zero 8row x 4k quads via per-quad flags (wave-uniform branch,
//     bit-exact), GEMM3 skipped via block-level s2any flag.

#define T_STEPS 100
#define BB      2048
#define N_IN    512
#define H1S     512
#define H2S     256
#define NOUT    5
#define BT      8
#define NTH     512

// ---- transpose x:(B*N, T) -> xt:(T, B*N) ----
__global__ __launch_bounds__(256)
void transpose_kernel(const float* __restrict__ x, float* __restrict__ xt) {
    __shared__ float tile[32 * 101];
    const long i0 = (long)blockIdx.x * 32;
    const float4* src = (const float4*)(x + i0 * T_STEPS);
    for (int f = threadIdx.x; f < 800; f += 256) {
        float4 v = src[f];
        int i  = f / 25;
        int t4 = (f % 25) * 4;
        float* d = &tile[i * 101 + t4];
        d[0] = v.x; d[1] = v.y; d[2] = v.z; d[3] = v.w;
    }
    __syncthreads();
    const int lane = threadIdx.x & 31;
    const int tg   = threadIdx.x >> 5;
    for (int t = tg; t < T_STEPS; t += 8) {
        xt[(long)t * (BB * N_IN) + i0 + lane] = tile[lane * 101 + t];
    }
}

// ---- generic 32x32 transpose: dst[c*R + r] = src[r*C + c] ----
__global__ __launch_bounds__(256)
void wtrans_kernel(const float* __restrict__ src, float* __restrict__ dst,
                   int R, int C) {
    __shared__ float tl[32][33];
    const int c0 = blockIdx.x * 32, r0 = blockIdx.y * 32;
    const int lx = threadIdx.x & 31, ly = threadIdx.x >> 5;
    for (int i = ly; i < 32; i += 8)
        tl[i][lx] = src[(size_t)(r0 + i) * C + c0 + lx];
    __syncthreads();
    for (int i = ly; i < 32; i += 8)
        dst[(size_t)(c0 + i) * R + r0 + lx] = tl[lx][i];
}

__device__ __forceinline__ void lif4(float4 h, float4& v, float4& sp) {
    v.x += (h.x - v.x) * 0.5f; v.y += (h.y - v.y) * 0.5f;
    v.z += (h.z - v.z) * 0.5f; v.w += (h.w - v.w) * 0.5f;
    sp.x = (v.x >= 1.0f) ? 1.0f : 0.0f; if (v.x >= 1.0f) v.x = 0.0f;
    sp.y = (v.y >= 1.0f) ? 1.0f : 0.0f; if (v.y >= 1.0f) v.y = 0.0f;
    sp.z = (v.z >= 1.0f) ? 1.0f : 0.0f; if (v.z >= 1.0f) v.z = 0.0f;
    sp.w = (v.w >= 1.0f) ? 1.0f : 0.0f; if (v.w >= 1.0f) v.w = 0.0f;
}

#define G2Q(QI, C) { float4 w = wk[QI * 64];                                    \
    _Pragma("unroll") for (int r = 0; r < 8; ++r) {                             \
        acc2[r].x += a[r].C * w.x; acc2[r].y += a[r].C * w.y;                   \
        acc2[r].z += a[r].C * w.z; acc2[r].w += a[r].C * w.w; } }

template <bool USE_XT>
__global__ __launch_bounds__(NTH, 2)
void snn_kernel(const float* __restrict__ xsrc,
                const float* __restrict__ W1t,   // (512 k, 512 j)
                const float* __restrict__ b1,
                const float* __restrict__ W2t,   // (512 k, 256 j)
                const float* __restrict__ b2,
                const float* __restrict__ Wo,    // (5, 256)
                const float* __restrict__ bo,
                float* __restrict__ out)
{
    __shared__ float scratch[16384];             // 64KB reduce scratch
    __shared__ float xb[2][4096];                // 32KB x tiles (t0, t1)
    __shared__ float s1[4096];                   // 16KB spikes L1
    __shared__ float s2[2048];                   // 8KB  spikes L2
    __shared__ float woL[1280];                  // 5KB  Wo cache
    __shared__ float part[320];
    __shared__ unsigned long long flg1[128];     // per-quad spike flags (8 rows x byte)
    __shared__ int s2any;

    const int tid = threadIdx.x;
    const int b0  = blockIdx.x * BT;

    const int jg1 = tid & 127, kg1 = tid >> 7;   // GEMM1: j=jg1*4, k in [kg1*128,+128)
    const int jg2 = tid & 63,  kg2 = tid >> 6;   // GEMM2: j=jg2*4, k in [kg2*64,+64)
    const int rr  = tid >> 6;                    // reduce: batch row
    const int ro = tid >> 3, cc3 = tid & 7;
    const int r3 = ro / 5, o3 = ro - 5 * r3;     // valid tid<320
    const int rf = tid / 5, of = tid - 5 * rf;   // valid tid<40

    for (int i = tid; i < NOUT * H2S; i += NTH) woL[i] = Wo[i];
    if (tid == 0) s2any = 0;

    float4 b1v[2], b2v;
    {
        const int jr = (tid & 63) * 4;
        b1v[0] = *(const float4*)&b1[jr];
        b1v[1] = *(const float4*)&b1[256 + jr];
        b2v    = *(const float4*)&b2[jr];
    }
    float4 v1[2], v2;
    v1[0] = make_float4(0.f,0.f,0.f,0.f); v1[1] = v1[0]; v2 = v1[0];
    float vo = 0.0f, osum = 0.0f, bor = (tid < 40) ? bo[of] : 0.0f;

    float4* sc4  = (float4*)scratch;
    float4* xb40 = (float4*)xb[0];
    float4* xb41 = (float4*)xb[1];
    float4* s1f4 = (float4*)s1;
    float4* s2f4 = (float4*)s2;
    const float4* w1p = ((const float4*)W1t) + jg1;  // row k: k*128 float4
    const float4* w2p = ((const float4*)W2t) + jg2;  // row k: k*64 float4

    for (int t0 = 0; t0 < T_STEPS; t0 += 2) {
        // ---- stage two x tiles ----
        if (USE_XT) {
            const float4* src0 = (const float4*)(xsrc + (size_t)t0 * (BB * N_IN)
                                                 + (size_t)b0 * N_IN);
            const float4* src1 = src0 + (BB * N_IN) / 4;
            xb40[tid] = src0[tid]; xb40[tid + NTH] = src0[tid + NTH];
            xb41[tid] = src1[tid]; xb41[tid + NTH] = src1[tid + NTH];
        } else {
#pragma unroll
            for (int e = 0; e < 8; ++e) {
                int i = tid + e * NTH;
                // t0 even -> 8-byte aligned float2 covering (t0, t0+1)
                float2 v = *(const float2*)&xsrc[((size_t)(b0 + (i >> 9)) * N_IN
                                                 + (i & 511)) * T_STEPS + t0];
                xb[0][i] = v.x; xb[1][i] = v.y;
            }
        }
        __syncthreads();                                      // A

        // ---- GEMM1 over BOTH timesteps: one W1 pass, two accumulators ----
        float4 acc0[8], acc1[8];
#pragma unroll
        for (int r = 0; r < 8; ++r) {
            acc0[r] = make_float4(0.f,0.f,0.f,0.f);
            acc1[r] = make_float4(0.f,0.f,0.f,0.f);
        }
        {
            const int kb4 = kg1 * 32;
#pragma unroll 1
            for (int k4 = 0; k4 < 32; ++k4) {
                float4 a0[8], a1[8];
#pragma unroll
                for (int r = 0; r < 8; ++r) {
                    a0[r] = xb40[r * 128 + kb4 + k4];
                    a1[r] = xb41[r * 128 + kb4 + k4];
                }
                const float4* wk = w1p + (size_t)(kb4 + k4) * 512;
#define G1Q(QI, C) { float4 w = wk[QI * 128];                                   \
    _Pragma("unroll") for (int r = 0; r < 8; ++r) {                             \
        acc0[r].x += a0[r].C * w.x; acc0[r].y += a0[r].C * w.y;                 \
        acc0[r].z += a0[r].C * w.z; acc0[r].w += a0[r].C * w.w; }               \
    _Pragma("unroll") for (int r = 0; r < 8; ++r) {                             \
        acc1[r].x += a1[r].C * w.x; acc1[r].y += a1[r].C * w.y;                 \
        acc1[r].z += a1[r].C * w.z; acc1[r].w += a1[r].C * w.w; } }
                G1Q(0, x) G1Q(1, y) G1Q(2, z) G1Q(3, w)
#undef G1Q
            }
        }

        // ---- per-timestep tail (tau unrolled -> static acc selection) ----
#pragma unroll
        for (int tau = 0; tau < 2; ++tau) {
            // partials -> scratch. Last scratch read was pre-F of previous
            // tail (or previous pair); barriers A / F separate. Safe.
#pragma unroll
            for (int r = 0; r < 8; ++r)
                sc4[(kg1 * 8 + r) * 128 + jg1] = tau ? acc1[r] : acc0[r];
            __syncthreads();                                  // C

            // ---- reduce1 + LIF1 -> s1 + quad spike flags ----
#pragma unroll
            for (int c = 0; c < 2; ++c) {
                float4 h = b1v[c];
#pragma unroll
                for (int kg = 0; kg < 4; ++kg) {
                    float4 p = sc4[(kg * 8 + rr) * 128 + c * 64 + (tid & 63)];
                    h.x += p.x; h.y += p.y; h.z += p.z; h.w += p.w;
                }
                float4 sp; lif4(h, v1[c], sp);
                s1f4[rr * 128 + c * 64 + (tid & 63)] = sp;
                ((unsigned char*)flg1)[(c * 64 + (tid & 63)) * 8 + rr] =
                    (sp.x + sp.y + sp.z + sp.w > 0.0f) ? 1 : 0;
            }
            __syncthreads();                                  // D
            if (tid == 0) s2any = 0;   // prev read pre-A; next write post-E

            // ---- GEMM2 with wave-uniform sparsity skip ----
            float4 acc2[8];
#pragma unroll
            for (int r = 0; r < 8; ++r) acc2[r] = make_float4(0.f,0.f,0.f,0.f);
            {
                const int kq0 = kg2 * 16;
#pragma unroll 1
                for (int k4 = 0; k4 < 16; ++k4) {
                    const int kb = kq0 + k4;
                    // kg2 = tid>>6 is wave-uniform -> uniform branch.
                    // Skipped quads contribute exactly 0 -> bit-exact.
                    if (flg1[kb] != 0ULL) {
                        float4 a[8];
#pragma unroll
                        for (int r = 0; r < 8; ++r) a[r] = s1f4[r * 128 + kb];
                        const float4* wk = w2p + (size_t)kb * 256;
                        G2Q(0, x) G2Q(1, y) G2Q(2, z) G2Q(3, w)
                    }
                }
            }
            // scratch last read pre-D; safe without extra barrier
#pragma unroll
            for (int r = 0; r < 8; ++r) sc4[(kg2 * 8 + r) * 64 + jg2] = acc2[r];
            __syncthreads();                                  // E

            // ---- reduce2 + LIF2 -> s2 (+ any-spike flag) ----
            {
                float4 h = b2v;
#pragma unroll
                for (int kg = 0; kg < 8; ++kg) {
                    float4 p = sc4[(kg * 8 + rr) * 64 + (tid & 63)];
                    h.x += p.x; h.y += p.y; h.z += p.z; h.w += p.w;
                }
                float4 sp; lif4(h, v2, sp);
                s2f4[rr * 64 + (tid & 63)] = sp;
                if (sp.x + sp.y + sp.z + sp.w > 0.0f) s2any = 1;
            }
            __syncthreads();                                  // F
            const int sk3 = s2any;   // block-uniform

            // ---- GEMM3 (only if any layer-2 spike) ----
            if (sk3) {
                if (tid < 320) {
                    const float4* sp2 = s2f4 + r3 * 64 + cc3 * 8;
                    const float4* wo4 = ((const float4*)woL) + o3 * 64 + cc3 * 8;
                    float p = 0.0f;
#pragma unroll
                    for (int k = 0; k < 8; ++k) {
                        float4 a = sp2[k], w = wo4[k];
                        p += a.x * w.x + a.y * w.y + a.z * w.z + a.w * w.w;
                    }
                    part[tid] = p;
                }
                __syncthreads();                              // G
            }
            if (tid < 40) {
                float o_cur = bor;
                if (sk3) {
#pragma unroll
                    for (int i = 0; i < 8; ++i) o_cur += part[tid * 8 + i];
                }
                float v = vo + (o_cur - vo) * 0.5f;
                if (v >= 1.0f) { osum += 1.0f; vo = 0.0f; }
                else           { vo = v; }
            }
        } // tau
    }

    if (tid < 40) out[(size_t)(b0 + rf) * NOUT + of] = osum / (float)T_STEPS;
}
#undef G2Q

extern "C" void kernel_launch(void* const* d_in, const int* in_sizes, int n_in,
                              void* d_out, int out_size, void* d_ws, size_t ws_size,
                              hipStream_t stream) {
    const float* x  = (const float*)d_in[0];
    const float* W1 = (const float*)d_in[1];
    const float* b1 = (const float*)d_in[2];
    const float* W2 = (const float*)d_in[3];
    const float* b2 = (const float*)d_in[4];
    const float* Wo = (const float*)d_in[5];
    const float* bo = (const float*)d_in[6];
    float* out = (float*)d_out;

    const size_t xt_elems = (size_t)T_STEPS * BB * N_IN;
    const size_t w1t_elems = (size_t)H1S * N_IN;
    const size_t w2t_elems = (size_t)H2S * H1S;
    const size_t full_bytes = (xt_elems + w1t_elems + w2t_elems) * sizeof(float);

    if (ws_size >= full_bytes) {
        float* xt  = (float*)d_ws;
        float* w1t = xt + xt_elems;
        float* w2t = w1t + w1t_elems;
        transpose_kernel<<<(BB * N_IN) / 32, 256, 0, stream>>>(x, xt);
        wtrans_kernel<<<dim3(N_IN / 32, H1S / 32), 256, 0, stream>>>(W1, w1t, H1S, N_IN);
        wtrans_kernel<<<dim3(H1S / 32, H2S / 32), 256, 0, stream>>>(W2, w2t, H2S, H1S);
        snn_kernel<true><<<BB / BT, NTH, 0, stream>>>(xt, w1t, b1, w2t, b2, Wo, bo, out);
    } else {
        float* w1t = (float*)d_ws;
        float* w2t = w1t + w1t_elems;
        wtrans_kernel<<<dim3(N_IN / 32, H1S / 32), 256, 0, stream>>>(W1, w1t, H1S, N_IN);
        wtrans_kernel<<<dim3(H1S / 32, H2S / 32), 256, 0, stream>>>(W2, w2t, H2S, H1S);
        snn_kernel<false><<<BB / BT, NTH, 0, stream>>>(x, w1t, b1, w2t, b2, Wo, bo, out);
    }
}